// Round 8
// baseline (578.840 us; speedup 1.0000x reference)
//
#include <hip/hip_runtime.h>
#include <hip/hip_bf16.h>
#include <math.h>

#define HW   64
#define NPIX 4096
#define CCH  128
#define KC   1152   // 9*C
#define KF   2304   // 9*256 (final conv K)
#define SCALEF 10.0f

typedef __attribute__((ext_vector_type(8))) short bf16x8;
typedef __attribute__((ext_vector_type(4))) float f32x4;

__device__ inline void gload_lds16(const void* g, void* l) {
    __builtin_amdgcn_global_load_lds(
        (const __attribute__((address_space(1))) unsigned int*)g,
        (__attribute__((address_space(3))) unsigned int*)l, 16, 0, 0);
}

// ---------------- build bf16 patch matrix Pbf[n, 1152] ----------------
__global__ void k_build_Pbf(const float* __restrict__ x, __hip_bfloat16* __restrict__ P, int b) {
    int idx = blockIdx.x * blockDim.x + threadIdx.x;
    int n = idx / KC, t = idx - n * KC;
    int u = t / 384, v = (t / 128) % 3, c = t & 127;
    int h = n >> 6, w = n & 63;
    int hh = h + u - 1, ww = w + v - 1;
    float val = 0.f;
    if (hh >= 0 && hh < HW && ww >= 0 && ww < HW)
        val = x[((size_t)(b * NPIX) + hh * HW + ww) * CCH + c];
    P[(size_t)n * KC + t] = __float2bfloat16(val);
}

// ---------------- build transposed patch matrix Pt[1152, 4096] ----------------
__global__ void k_build_Pt(const float* __restrict__ x, __hip_bfloat16* __restrict__ Pt, int b) {
    int idx = blockIdx.x * blockDim.x + threadIdx.x;
    int j = idx >> 12, k = idx & 4095;
    int u = j / 384, v = (j / 128) % 3, c = j & 127;
    int h = k >> 6, w = k & 63;
    int hh = h + u - 1, ww = w + v - 1;
    float val = 0.f;
    if (hh >= 0 && hh < HW && ww >= 0 && ww < HW)
        val = x[((size_t)(b * NPIX) + hh * HW + ww) * CCH + c];
    Pt[idx] = __float2bfloat16(val);
}

// ---------------- per-patch norm ----------------
__global__ void k_colnorm(const __hip_bfloat16* __restrict__ P, float* __restrict__ cn) {
    int n = blockIdx.x;
    int tid = threadIdx.x;
    float s = 0.f;
    for (int t = tid; t < KC; t += 256) {
        float v = __bfloat162float(P[(size_t)n * KC + t]);
        s += v * v;
    }
    __shared__ float red[256];
    red[tid] = s; __syncthreads();
    for (int st = 128; st > 0; st >>= 1) {
        if (tid < st) red[tid] += red[tid + st];
        __syncthreads();
    }
    if (tid == 0) cn[n] = fmaxf(sqrtf(red[0]), 1e-4f);
}

// ---------------- mask validity mm[n] ----------------
__global__ void k_mm(const float* __restrict__ mask, float* __restrict__ mmv, int b) {
    int n = blockIdx.x * blockDim.x + threadIdx.x;
    if (n >= NPIX) return;
    int h = n >> 6, w = n & 63;
    float s = 0.f;
    for (int u = 0; u < 3; u++)
        for (int v = 0; v < 3; v++) {
            int hh = h + u - 1, ww = w + v - 1;
            if (hh >= 0 && hh < HW && ww >= 0 && ww < HW)
                s += mask[(size_t)b * NPIX + hh * HW + ww];
        }
    mmv[n] = ((s / 9.0f) == 1.0f) ? 1.0f : 0.0f;
}

// ---------------- GEMM1 symmetric: S = P P^T D, upper-triangle tiles only -------
// 528 blocks; tile (ti<=tj). Off-diagonal tiles write both (p,q) and (q,p).
__global__ __launch_bounds__(256) void k_gemm_sym(
    const __hip_bfloat16* __restrict__ A, float* __restrict__ C,
    const float* __restrict__ colnorm) {
    __shared__ __align__(16) __hip_bfloat16 As[2][128 * 64];
    __shared__ __align__(16) __hip_bfloat16 Bs[2][128 * 64];
    const int tid = threadIdx.x;
    const int l = tid & 63;
    const int wid = tid >> 6;
    const int wr = wid >> 1, wc = wid & 1;
    const int lane16 = l & 15, kgrp = l >> 4;
    // XCD-contiguous bands over 528 triangular tiles (528 = 8*66)
    const int id0 = blockIdx.x;
    int t = (id0 & 7) * 66 + (id0 >> 3);
    int ti = 0;
    while (t >= 32 - ti) { t -= 32 - ti; ti++; }
    const int tj = ti + t;
    const int p0 = ti * 128, q0 = tj * 128;
    const int srow = l >> 3;
    const int scol = ((l & 7) ^ srow) * 8;

    f32x4 acc[16];
    f32x4 zf; zf[0] = 0.f; zf[1] = 0.f; zf[2] = 0.f; zf[3] = 0.f;
    #pragma unroll
    for (int i = 0; i < 16; i++) acc[i] = zf;

    auto stage = [&](int buf, int k0) {
        #pragma unroll
        for (int tt = 0; tt < 4; tt++) {
            int r0 = wid * 32 + tt * 8;
            gload_lds16(A + (size_t)(p0 + r0 + srow) * KC + k0 + scol,
                        (char*)As[buf] + r0 * 128);
            gload_lds16(A + (size_t)(q0 + r0 + srow) * KC + k0 + scol,
                        (char*)Bs[buf] + r0 * 128);
        }
    };

    const int nst = KC >> 6;
    stage(0, 0);
    __syncthreads();
    int cur = 0;
    for (int s = 0; s < nst; ++s) {
        if (s + 1 < nst) stage(cur ^ 1, (s + 1) << 6);
        const char* Ab = (const char*)As[cur];
        const char* Bb = (const char*)Bs[cur];
        #pragma unroll
        for (int kh = 0; kh < 2; kh++) {
            bf16x8 af[4], bg[4];
            #pragma unroll
            for (int mi = 0; mi < 4; mi++) {
                int row = wr * 64 + mi * 16 + lane16;
                af[mi] = *(const bf16x8*)(Ab + row * 128 +
                         (((kgrp + 4 * kh) ^ (row & 7)) << 4));
            }
            #pragma unroll
            for (int ni = 0; ni < 4; ni++) {
                int row = wc * 64 + ni * 16 + lane16;
                bg[ni] = *(const bf16x8*)(Bb + row * 128 +
                         (((kgrp + 4 * kh) ^ (row & 7)) << 4));
            }
            #pragma unroll
            for (int mi = 0; mi < 4; mi++)
                #pragma unroll
                for (int ni = 0; ni < 4; ni++)
                    acc[mi * 4 + ni] = __builtin_amdgcn_mfma_f32_16x16x32_bf16(
                        af[mi], bg[ni], acc[mi * 4 + ni], 0, 0, 0);
        }
        __syncthreads();
        cur ^= 1;
    }

    float invq[4];
    #pragma unroll
    for (int ni = 0; ni < 4; ni++)
        invq[ni] = 1.0f / colnorm[q0 + wc * 64 + ni * 16 + lane16];
    float invp[4][4];
    #pragma unroll
    for (int mi = 0; mi < 4; mi++) {
        int rbase = p0 + wr * 64 + mi * 16 + kgrp * 4;
        #pragma unroll
        for (int j = 0; j < 4; j++)
            invp[mi][j] = 1.0f / colnorm[rbase + j];
    }
    #pragma unroll
    for (int mi = 0; mi < 4; mi++) {
        int rbase = p0 + wr * 64 + mi * 16 + kgrp * 4;
        #pragma unroll
        for (int ni = 0; ni < 4; ni++) {
            int col = q0 + wc * 64 + ni * 16 + lane16;
            f32x4 v = acc[mi * 4 + ni];
            #pragma unroll
            for (int j = 0; j < 4; j++)
                C[(size_t)(rbase + j) * NPIX + col] = v[j] * invq[ni];
            if (ti != tj) {   // mirror tile: S[q][p] = dot * inv[p], contiguous float4
                float4 tv;
                tv.x = v[0] * invp[mi][0]; tv.y = v[1] * invp[mi][1];
                tv.z = v[2] * invp[mi][2]; tv.w = v[3] * invp[mi][3];
                *(float4*)&C[(size_t)col * NPIX + rbase] = tv;
            }
        }
    }
}

// ---------------- MFMA GEMM (GEMM2): 128x128 tile, dbuf + swizzle, batch-z ------
__global__ __launch_bounds__(256) void k_mfma_gemm(
    const __hip_bfloat16* __restrict__ A, const __hip_bfloat16* __restrict__ B,
    float* __restrict__ C, int Ka, int ldc, size_t sA, size_t sB, size_t sC) {
    __shared__ __align__(16) __hip_bfloat16 As[2][128 * 64];
    __shared__ __align__(16) __hip_bfloat16 Bs[2][128 * 64];
    const int zb = blockIdx.z;
    A += (size_t)zb * sA; B += (size_t)zb * sB; C += (size_t)zb * sC;
    const int tid = threadIdx.x;
    const int l = tid & 63;
    const int wid = tid >> 6;
    const int wr = wid >> 1, wc = wid & 1;
    const int lane16 = l & 15, kgrp = l >> 4;
    const int gx = gridDim.x;
    const int nwg = gx * gridDim.y;
    const int id0 = blockIdx.y * gx + blockIdx.x;
    const int swzid = (id0 & 7) * (nwg >> 3) + (id0 >> 3);
    const int p0 = (swzid / gx) * 128, q0 = (swzid % gx) * 128;
    const int srow = l >> 3;
    const int scol = ((l & 7) ^ srow) * 8;

    f32x4 acc[16];
    f32x4 zf; zf[0] = 0.f; zf[1] = 0.f; zf[2] = 0.f; zf[3] = 0.f;
    #pragma unroll
    for (int i = 0; i < 16; i++) acc[i] = zf;

    auto stage = [&](int buf, int k0) {
        #pragma unroll
        for (int t = 0; t < 4; t++) {
            int r0 = wid * 32 + t * 8;
            gload_lds16(A + (size_t)(p0 + r0 + srow) * Ka + k0 + scol,
                        (char*)As[buf] + r0 * 128);
            gload_lds16(B + (size_t)(q0 + r0 + srow) * Ka + k0 + scol,
                        (char*)Bs[buf] + r0 * 128);
        }
    };

    const int nst = Ka >> 6;
    stage(0, 0);
    __syncthreads();
    int cur = 0;
    for (int s = 0; s < nst; ++s) {
        if (s + 1 < nst) stage(cur ^ 1, (s + 1) << 6);
        const char* Ab = (const char*)As[cur];
        const char* Bb = (const char*)Bs[cur];
        #pragma unroll
        for (int kh = 0; kh < 2; kh++) {
            bf16x8 af[4], bg[4];
            #pragma unroll
            for (int mi = 0; mi < 4; mi++) {
                int row = wr * 64 + mi * 16 + lane16;
                af[mi] = *(const bf16x8*)(Ab + row * 128 +
                         (((kgrp + 4 * kh) ^ (row & 7)) << 4));
            }
            #pragma unroll
            for (int ni = 0; ni < 4; ni++) {
                int row = wc * 64 + ni * 16 + lane16;
                bg[ni] = *(const bf16x8*)(Bb + row * 128 +
                         (((kgrp + 4 * kh) ^ (row & 7)) << 4));
            }
            #pragma unroll
            for (int mi = 0; mi < 4; mi++)
                #pragma unroll
                for (int ni = 0; ni < 4; ni++)
                    acc[mi * 4 + ni] = __builtin_amdgcn_mfma_f32_16x16x32_bf16(
                        af[mi], bg[ni], acc[mi * 4 + ni], 0, 0, 0);
        }
        __syncthreads();
        cur ^= 1;
    }

    #pragma unroll
    for (int mi = 0; mi < 4; mi++) {
        int rbase = p0 + wr * 64 + mi * 16 + kgrp * 4;
        #pragma unroll
        for (int ni = 0; ni < 4; ni++) {
            int col = q0 + wc * 64 + ni * 16 + lane16;
            f32x4 v = acc[mi * 4 + ni];
            #pragma unroll
            for (int j = 0; j < 4; j++)
                C[(size_t)(rbase + j) * ldc + col] = v[j];
        }
    }
}

// ---------------- fuse + mask + softmax -> bf16 Y (XCD-contiguous rows) ----------
__global__ void k_fusesm(const float* __restrict__ S, const float* __restrict__ mmv,
                         __hip_bfloat16* __restrict__ Y) {
    int blk = blockIdx.x;
    int p = ((blk & 7) << 9) | (blk >> 3);
    int tid = threadIdx.x;
    __shared__ float z[NPIX];
    __shared__ float red[256];
    int cmp = ((p & 63) << 6) | (p >> 6);
    const float* rowp[3][3];
    #pragma unroll
    for (int ei = 0; ei < 3; ei++)
        #pragma unroll
        for (int di = 0; di < 3; di++) {
            int cp2 = cmp + ei - 1;
            const float* rp = nullptr;
            if (cp2 >= 0 && cp2 < NPIX) {
                int prm = ((cp2 & 63) << 6) | (cp2 >> 6);
                int pa = prm + di - 1;
                if (pa >= 0 && pa < NPIX) rp = S + (size_t)pa * NPIX;
            }
            rowp[ei][di] = rp;
        }
    float lmax = -1e30f;
    for (int q = tid; q < NPIX; q += 256) {
        int cmq = ((q & 63) << 6) | (q >> 6);
        float acc = 0.f;
        #pragma unroll
        for (int ei = 0; ei < 3; ei++) {
            int cq2 = cmq + ei - 1;
            if (cq2 < 0 || cq2 >= NPIX) continue;
            int qrm = ((cq2 & 63) << 6) | (cq2 >> 6);
            #pragma unroll
            for (int di = 0; di < 3; di++) {
                int qa = qrm + di - 1;
                const float* rp = rowp[ei][di];
                if (rp && qa >= 0 && qa < NPIX) acc += rp[qa];
            }
        }
        float zz = acc * mmv[q] * SCALEF;
        z[q] = zz;
        lmax = fmaxf(lmax, zz);
    }
    red[tid] = lmax; __syncthreads();
    for (int st = 128; st > 0; st >>= 1) {
        if (tid < st) red[tid] = fmaxf(red[tid], red[tid + st]);
        __syncthreads();
    }
    float gmax = red[0];
    __syncthreads();
    float lsum = 0.f;
    for (int q = tid; q < NPIX; q += 256) {
        float e = expf(z[q] - gmax);
        z[q] = e;
        lsum += e;
    }
    red[tid] = lsum; __syncthreads();
    for (int st = 128; st > 0; st >>= 1) {
        if (tid < st) red[tid] += red[tid + st];
        __syncthreads();
    }
    float invs = 1.0f / red[0];
    for (int q = tid; q < NPIX; q += 256)
        Y[(size_t)p * NPIX + q] = __float2bfloat16(z[q] * invs * mmv[q]);
}

// ---------------- deconv gather + concat with x -> hi/lo bf16 ----------------
__global__ void k_deconv(const float* __restrict__ O2, const float* __restrict__ x,
                         __hip_bfloat16* __restrict__ ych, __hip_bfloat16* __restrict__ ycl,
                         int bsel, size_t sO2) {
    int idx = blockIdx.x * blockDim.x + threadIdx.x;
    int b = (bsel >= 0) ? bsel : (idx >> 19);
    int loc = idx & ((1 << 19) - 1);
    int p = loc >> 7, c = loc & 127;
    int h = p >> 6, w = p & 63;
    const float* O2b = O2 + ((bsel >= 0) ? 0 : (size_t)b * sO2);
    float acc = 0.f;
    #pragma unroll
    for (int u = 0; u < 3; u++) {
        int hh = h + 1 - u;
        if (hh < 0 || hh >= HW) continue;
        #pragma unroll
        for (int v = 0; v < 3; v++) {
            int ww = w + 1 - v;
            if (ww < 0 || ww >= HW) continue;
            acc += O2b[(size_t)(hh * HW + ww) * KC + (u * 3 + v) * CCH + c];
        }
    }
    float xv = x[((size_t)b * NPIX + p) * CCH + c];
    size_t base = (size_t)b * NPIX * 256 + (size_t)p * 256;
    __hip_bfloat16 ah = __float2bfloat16(acc);
    __hip_bfloat16 xh = __float2bfloat16(xv);
    ych[base + c] = ah;
    ych[base + 128 + c] = xh;
    ycl[base + c] = __float2bfloat16(acc - __bfloat162float(ah));
    ycl[base + 128 + c] = __float2bfloat16(xv - __bfloat162float(xh));
}

// ---------------- split+transpose weights Wc/W2 ----------------
__global__ void k_wsplit(const float* __restrict__ Wc, const float* __restrict__ W2,
                         __hip_bfloat16* __restrict__ wtc_h, __hip_bfloat16* __restrict__ wtc_l,
                         __hip_bfloat16* __restrict__ wt2_h, __hip_bfloat16* __restrict__ wt2_l) {
    int idx = blockIdx.x * blockDim.x + threadIdx.x;
    int m = idx / (128 * KF);
    int rem = idx - m * 128 * KF;
    int j = rem / KF, k = rem - j * KF;
    const float* src = m ? W2 : Wc;
    float v = src[(size_t)k * 128 + j];
    __hip_bfloat16 hi = __float2bfloat16(v);
    __hip_bfloat16 lo = __float2bfloat16(v - __bfloat162float(hi));
    (m ? wt2_h : wtc_h)[(size_t)j * KF + k] = hi;
    (m ? wt2_l : wtc_l)[(size_t)j * KF + k] = lo;
}

// ---------------- split+transpose W1 ----------------
__global__ void k_wsplit1(const float* __restrict__ W1,
                          __hip_bfloat16* __restrict__ w1t_h, __hip_bfloat16* __restrict__ w1t_l) {
    int idx = blockIdx.x * blockDim.x + threadIdx.x;
    int j = idx >> 8, k = idx & 255;
    float v = W1[(size_t)k * 128 + j];
    __hip_bfloat16 hi = __float2bfloat16(v);
    __hip_bfloat16 lo = __float2bfloat16(v - __bfloat162float(hi));
    w1t_h[(size_t)j * 256 + k] = hi;
    w1t_l[(size_t)j * 256 + k] = lo;
}

__global__ void k_zero(float* __restrict__ zp) {
    if (threadIdx.x < 64) zp[threadIdx.x] = 0.f;
}

// ---------------- final conv via split-bf16 MFMA, W1 gate folded in ----------------
__global__ __launch_bounds__(256) void k_final_mfma(
    const __hip_bfloat16* __restrict__ ych, const __hip_bfloat16* __restrict__ ycl,
    const __hip_bfloat16* __restrict__ wtc_h, const __hip_bfloat16* __restrict__ wtc_l,
    const __hip_bfloat16* __restrict__ wt2_h, const __hip_bfloat16* __restrict__ wt2_l,
    const __hip_bfloat16* __restrict__ w1t_h, const __hip_bfloat16* __restrict__ w1t_l,
    const float* __restrict__ bc, const float* __restrict__ b1,
    const float* __restrict__ b2, const float* __restrict__ zpage,
    float* __restrict__ outp) {
    __shared__ __align__(16) char As_h[2048], As_l[2048];
    __shared__ __align__(16) char Bs_h[32768], Bs_l[32768];
    const int tid = threadIdx.x;
    const int lane = tid & 63, wv = tid >> 6;
    const int lane16 = lane & 15, kgrp = lane >> 4;
    const int gblk = blockIdx.x;
    const int b = gblk >> 8;
    const int p0l = (gblk & 255) * 16;
    const __hip_bfloat16* ybh = ych + (size_t)b * NPIX * 256;
    const __hip_bfloat16* ybl = ycl + (size_t)b * NPIX * 256;
    const int srow8 = lane >> 3;
    const int c16 = lane & 7;
    const int swc = c16 ^ srow8;

    const int arow = ((wv & 1) << 3) + srow8;
    const int apr = p0l + arow;
    const int ah_ = apr >> 6, aw_ = apr & 63;
    char* const a_ldst = ((wv >> 1) ? As_l : As_h) + ((wv & 1) << 10);
    const __hip_bfloat16* const a_base = (wv >> 1) ? ybl : ybh;

    const char* bsrc_h[8];
    const char* bsrc_l[8];
    #pragma unroll
    for (int r = 0; r < 8; r++) {
        int q = r * 4 + wv;
        int row = q * 8 + srow8;
        const __hip_bfloat16* mh = (row < 128) ? (wtc_h + (size_t)row * KF)
                                               : (wt2_h + (size_t)(row - 128) * KF);
        const __hip_bfloat16* ml = (row < 128) ? (wtc_l + (size_t)row * KF)
                                               : (wt2_l + (size_t)(row - 128) * KF);
        bsrc_h[r] = (const char*)(mh + swc * 8);
        bsrc_l[r] = (const char*)(ml + swc * 8);
    }

    f32x4 acc[4];
    f32x4 zf; zf[0] = 0.f; zf[1] = 0.f; zf[2] = 0.f; zf[3] = 0.f;
    #pragma unroll
    for (int f = 0; f < 4; f++) acc[f] = zf;

    for (int it = 0; it < 36; ++it) {
        const int k0 = it * 64;
        const int tap = k0 >> 8, i0 = k0 & 255;
        const int di = tap / 3, dj = tap - di * 3;
        {
            int hh = ah_ + di - 1, ww = aw_ + dj - 1;
            const void* src;
            if (hh >= 0 && hh < HW && ww >= 0 && ww < HW)
                src = a_base + ((size_t)(hh * HW + ww) * 256 + i0 + swc * 8);
            else
                src = (const char*)zpage + c16 * 16;
            gload_lds16(src, a_ldst);
        }
        #pragma unroll
        for (int r = 0; r < 8; r++) {
            int q = r * 4 + wv;
            gload_lds16(bsrc_h[r] + (size_t)it * 128, Bs_h + (q << 10));
            gload_lds16(bsrc_l[r] + (size_t)it * 128, Bs_l + (q << 10));
        }
        __syncthreads();
        #pragma unroll
        for (int kh = 0; kh < 2; kh++) {
            const int chunk = kgrp + 4 * kh;
            const int abyte = lane16 * 128 + ((chunk ^ (lane16 & 7)) << 4);
            bf16x8 ah = *(const bf16x8*)(As_h + abyte);
            bf16x8 al = *(const bf16x8*)(As_l + abyte);
            #pragma unroll
            for (int f = 0; f < 4; f++) {
                int brow = ((f < 2) ? 0 : 128) + wv * 32 + ((f & 1) << 4) + lane16;
                int bbyte = brow * 128 + ((chunk ^ (brow & 7)) << 4);
                bf16x8 bh = *(const bf16x8*)(Bs_h + bbyte);
                bf16x8 bl = *(const bf16x8*)(Bs_l + bbyte);
                acc[f] = __builtin_amdgcn_mfma_f32_16x16x32_bf16(ah, bh, acc[f], 0, 0, 0);
                acc[f] = __builtin_amdgcn_mfma_f32_16x16x32_bf16(ah, bl, acc[f], 0, 0, 0);
                acc[f] = __builtin_amdgcn_mfma_f32_16x16x32_bf16(al, bh, acc[f], 0, 0, 0);
            }
        }
        __syncthreads();
    }

    f32x4 acc1[2];
    acc1[0] = zf; acc1[1] = zf;
    for (int ki = 0; ki < 4; ++ki) {
        gload_lds16(a_base + ((size_t)(ah_ * HW + aw_) * 256 + ki * 64 + swc * 8), a_ldst);
        #pragma unroll
        for (int r = 0; r < 4; r++) {
            int q = r * 4 + wv;
            int row = q * 8 + srow8;
            gload_lds16((const char*)(w1t_h + (size_t)row * 256 + ki * 64 + swc * 8),
                        Bs_h + (q << 10));
            gload_lds16((const char*)(w1t_l + (size_t)row * 256 + ki * 64 + swc * 8),
                        Bs_l + (q << 10));
        }
        __syncthreads();
        #pragma unroll
        for (int kh = 0; kh < 2; kh++) {
            const int chunk = kgrp + 4 * kh;
            const int abyte = lane16 * 128 + ((chunk ^ (lane16 & 7)) << 4);
            bf16x8 ah = *(const bf16x8*)(As_h + abyte);
            bf16x8 al = *(const bf16x8*)(As_l + abyte);
            #pragma unroll
            for (int g = 0; g < 2; g++) {
                int brow = wv * 32 + (g << 4) + lane16;
                int bbyte = brow * 128 + ((chunk ^ (brow & 7)) << 4);
                bf16x8 bh = *(const bf16x8*)(Bs_h + bbyte);
                bf16x8 bl = *(const bf16x8*)(Bs_l + bbyte);
                acc1[g] = __builtin_amdgcn_mfma_f32_16x16x32_bf16(ah, bh, acc1[g], 0, 0, 0);
                acc1[g] = __builtin_amdgcn_mfma_f32_16x16x32_bf16(ah, bl, acc1[g], 0, 0, 0);
                acc1[g] = __builtin_amdgcn_mfma_f32_16x16x32_bf16(al, bh, acc1[g], 0, 0, 0);
            }
        }
        __syncthreads();
    }

    #pragma unroll
    for (int fc = 0; fc < 2; fc++) {
        int col = wv * 32 + (fc << 4) + lane16;
        float bcv = bc[col], b1v = b1[col], b2v = b2[col];
        #pragma unroll
        for (int j = 0; j < 4; j++) {
            int px = kgrp * 4 + j;
            size_t gp = (size_t)gblk * 16 + px;
            float core = acc[fc][j] + bcv;
            float g2 = acc[fc + 2][j] + b2v;
            float a1 = acc1[fc][j] + b1v;
            float s1 = 1.f / (1.f + expf(-a1));
            float s2 = 1.f / (1.f + expf(-g2));
            outp[gp * 128 + col] = 0.5f * (s1 + s2) * core;
        }
    }
}

extern "C" void kernel_launch(void* const* d_in, const int* in_sizes, int n_in,
                              void* d_out, int out_size, void* d_ws, size_t ws_size,
                              hipStream_t stream) {
    const float* x    = (const float*)d_in[0];
    const float* mask = (const float*)d_in[1];
    const float* Wc   = (const float*)d_in[2];
    const float* bc   = (const float*)d_in[3];
    const float* W1   = (const float*)d_in[4];
    const float* b1   = (const float*)d_in[5];
    const float* W2   = (const float*)d_in[6];
    const float* b2   = (const float*)d_in[7];
    float* outp = (float*)d_out;

    char* ws = (char*)d_ws;
    const size_t NEED_BIG = 211190016UL;
    const bool big = (ws_size >= NEED_BIG);

    __hip_bfloat16* Pbf;  __hip_bfloat16* Pt0;  size_t ptStride;
    float* S;  __hip_bfloat16* Y0;  size_t yStride;
    float* O2; size_t o2Stride;
    __hip_bfloat16 *ych, *ycl, *wtc_h, *wtc_l, *wt2_h, *wt2_l, *w1t_h, *w1t_l;
    float *colnorm, *mmv, *zpage;

    if (big) {
        Pbf   = (__hip_bfloat16*)(ws + 0);
        Pt0   = (__hip_bfloat16*)(ws + 9437184UL);   ptStride = (size_t)KC * NPIX;
        S     = (float*)(ws + 28311552UL);
        Y0    = (__hip_bfloat16*)(ws + 95420416UL);  yStride  = (size_t)NPIX * NPIX;
        O2    = (float*)(ws + 162529280UL);          o2Stride = (size_t)NPIX * KC;
        ych   = (__hip_bfloat16*)(ws + 200278016UL);
        ycl   = (__hip_bfloat16*)(ws + 204472320UL);
        wtc_h = (__hip_bfloat16*)(ws + 208666624UL);
        wtc_l = (__hip_bfloat16*)(ws + 209256448UL);
        wt2_h = (__hip_bfloat16*)(ws + 209846272UL);
        wt2_l = (__hip_bfloat16*)(ws + 210436096UL);
        w1t_h = (__hip_bfloat16*)(ws + 211025920UL);
        w1t_l = (__hip_bfloat16*)(ws + 211091456UL);
        colnorm = (float*)(ws + 211156992UL);
        mmv     = (float*)(ws + 211173376UL);
        zpage   = (float*)(ws + 211189760UL);
    } else {
        Pbf   = (__hip_bfloat16*)(ws + 0);
        Pt0   = (__hip_bfloat16*)(ws + 9437184UL);   ptStride = 0;
        S     = (float*)(ws + 18874368UL);
        Y0    = (__hip_bfloat16*)(ws + 85983232UL);  yStride  = 0;
        O2    = (float*)(ws + 119537664UL);          o2Stride = 0;
        ych   = (__hip_bfloat16*)(ws + 138412032UL);
        ycl   = (__hip_bfloat16*)(ws + 142606336UL);
        wtc_h = (__hip_bfloat16*)(ws + 146800640UL);
        wtc_l = (__hip_bfloat16*)(ws + 147390464UL);
        wt2_h = (__hip_bfloat16*)(ws + 147980288UL);
        wt2_l = (__hip_bfloat16*)(ws + 148570112UL);
        w1t_h = (__hip_bfloat16*)(ws + 149159936UL);
        w1t_l = (__hip_bfloat16*)(ws + 149225472UL);
        colnorm = (float*)(ws + 149291008UL);
        mmv     = (float*)(ws + 149307392UL);
        zpage   = (float*)(ws + 149323776UL);
    }

    hipLaunchKernelGGL(k_zero, dim3(1), dim3(64), 0, stream, zpage);
    hipLaunchKernelGGL(k_wsplit, dim3(2 * 128 * KF / 256), dim3(256), 0, stream,
                       Wc, W2, wtc_h, wtc_l, wt2_h, wt2_l);
    hipLaunchKernelGGL(k_wsplit1, dim3(128 * 256 / 256), dim3(256), 0, stream,
                       W1, w1t_h, w1t_l);

    for (int b = 0; b < 2; b++) {
        hipLaunchKernelGGL(k_build_Pbf, dim3((NPIX * KC) / 256), dim3(256), 0, stream, x, Pbf, b);
        hipLaunchKernelGGL(k_build_Pt, dim3((KC * NPIX) / 256), dim3(256), 0, stream,
                           x, Pt0 + (size_t)b * ptStride, b);
        hipLaunchKernelGGL(k_colnorm, dim3(NPIX), dim3(256), 0, stream, Pbf, colnorm);
        hipLaunchKernelGGL(k_mm, dim3(NPIX / 256), dim3(256), 0, stream, mask, mmv, b);
        hipLaunchKernelGGL(k_gemm_sym, dim3(528), dim3(256), 0, stream, Pbf, S, colnorm);
        hipLaunchKernelGGL(k_fusesm, dim3(NPIX), dim3(256), 0, stream,
                           S, mmv, Y0 + (size_t)b * yStride);
        if (!big) {
            hipLaunchKernelGGL(k_mfma_gemm, dim3(9, 32, 1), dim3(256), 0, stream,
                               Y0, Pt0, O2, NPIX, KC, (size_t)0, (size_t)0, (size_t)0);
            hipLaunchKernelGGL(k_deconv, dim3((NPIX * CCH) / 256), dim3(256), 0, stream,
                               O2, x, ych, ycl, b, (size_t)0);
        }
    }
    if (big) {
        hipLaunchKernelGGL(k_mfma_gemm, dim3(9, 32, 2), dim3(256), 0, stream,
                           Y0, Pt0, O2, NPIX, KC, yStride, ptStride, o2Stride);
        hipLaunchKernelGGL(k_deconv, dim3((2 * NPIX * CCH) / 256), dim3(256), 0, stream,
                           O2, x, ych, ycl, -1, o2Stride);
    }
    hipLaunchKernelGGL(k_final_mfma, dim3(512), dim3(256), 0, stream,
                       ych, ycl, wtc_h, wtc_l, wt2_h, wt2_l, w1t_h, w1t_l,
                       bc, b1, b2, zpage, outp);
}

// Round 9
// 538.547 us; speedup vs baseline: 1.0748x; 1.0748x over previous
//
#include <hip/hip_runtime.h>
#include <hip/hip_bf16.h>
#include <math.h>

#define HW   64
#define NPIX 4096
#define CCH  128
#define KC   1152   // 9*C
#define KF   2304   // 9*256 (final conv K)
#define SCALEF 10.0f

typedef __attribute__((ext_vector_type(8))) short bf16x8;
typedef __attribute__((ext_vector_type(4))) float f32x4;

__device__ inline void gload_lds16(const void* g, void* l) {
    __builtin_amdgcn_global_load_lds(
        (const __attribute__((address_space(1))) unsigned int*)g,
        (__attribute__((address_space(3))) unsigned int*)l, 16, 0, 0);
}

// ---------------- build bf16 patch matrix Pbf[n, 1152] ----------------
__global__ void k_build_Pbf(const float* __restrict__ x, __hip_bfloat16* __restrict__ P, int b) {
    int idx = blockIdx.x * blockDim.x + threadIdx.x;
    int n = idx / KC, t = idx - n * KC;
    int u = t / 384, v = (t / 128) % 3, c = t & 127;
    int h = n >> 6, w = n & 63;
    int hh = h + u - 1, ww = w + v - 1;
    float val = 0.f;
    if (hh >= 0 && hh < HW && ww >= 0 && ww < HW)
        val = x[((size_t)(b * NPIX) + hh * HW + ww) * CCH + c];
    P[(size_t)n * KC + t] = __float2bfloat16(val);
}

// ---------------- build transposed patch matrix Pt[1152, 4096] ----------------
__global__ void k_build_Pt(const float* __restrict__ x, __hip_bfloat16* __restrict__ Pt, int b) {
    int idx = blockIdx.x * blockDim.x + threadIdx.x;
    int j = idx >> 12, k = idx & 4095;
    int u = j / 384, v = (j / 128) % 3, c = j & 127;
    int h = k >> 6, w = k & 63;
    int hh = h + u - 1, ww = w + v - 1;
    float val = 0.f;
    if (hh >= 0 && hh < HW && ww >= 0 && ww < HW)
        val = x[((size_t)(b * NPIX) + hh * HW + ww) * CCH + c];
    Pt[idx] = __float2bfloat16(val);
}

// ---------------- per-patch norm ----------------
__global__ void k_colnorm(const __hip_bfloat16* __restrict__ P, float* __restrict__ cn) {
    int n = blockIdx.x;
    int tid = threadIdx.x;
    float s = 0.f;
    for (int t = tid; t < KC; t += 256) {
        float v = __bfloat162float(P[(size_t)n * KC + t]);
        s += v * v;
    }
    __shared__ float red[256];
    red[tid] = s; __syncthreads();
    for (int st = 128; st > 0; st >>= 1) {
        if (tid < st) red[tid] += red[tid + st];
        __syncthreads();
    }
    if (tid == 0) cn[n] = fmaxf(sqrtf(red[0]), 1e-4f);
}

// ---------------- mask validity mm[n] ----------------
__global__ void k_mm(const float* __restrict__ mask, float* __restrict__ mmv, int b) {
    int n = blockIdx.x * blockDim.x + threadIdx.x;
    if (n >= NPIX) return;
    int h = n >> 6, w = n & 63;
    float s = 0.f;
    for (int u = 0; u < 3; u++)
        for (int v = 0; v < 3; v++) {
            int hh = h + u - 1, ww = w + v - 1;
            if (hh >= 0 && hh < HW && ww >= 0 && ww < HW)
                s += mask[(size_t)b * NPIX + hh * HW + ww];
        }
    mmv[n] = ((s / 9.0f) == 1.0f) ? 1.0f : 0.0f;
}

// ---------------- GEMM1 symmetric: S = P P^T D, upper-triangle tiles ------------
// BK=32 dbuf: LDS 32KB -> 4 blocks/CU -> 528 blocks fit in ONE resident round.
__global__ __launch_bounds__(256) void k_gemm_sym(
    const __hip_bfloat16* __restrict__ A, float* __restrict__ C,
    const float* __restrict__ colnorm) {
    __shared__ __align__(16) __hip_bfloat16 As[2][128 * 32];
    __shared__ __align__(16) __hip_bfloat16 Bs[2][128 * 32];
    const int tid = threadIdx.x;
    const int l = tid & 63;
    const int wid = tid >> 6;
    const int wr = wid >> 1, wc = wid & 1;
    const int lane16 = l & 15, kgrp = l >> 4;
    const int id0 = blockIdx.x;
    int t = (id0 & 7) * 66 + (id0 >> 3);
    int ti = 0;
    while (t >= 32 - ti) { t -= 32 - ti; ti++; }
    const int tj = ti + t;
    const int p0 = ti * 128, q0 = tj * 128;
    const int srow16 = l >> 2;        // 0..15 (row within 16-row chunk)
    const int scol8 = (l & 3) * 8;    // bf16 element offset

    f32x4 acc[16];
    f32x4 zf; zf[0] = 0.f; zf[1] = 0.f; zf[2] = 0.f; zf[3] = 0.f;
    #pragma unroll
    for (int i = 0; i < 16; i++) acc[i] = zf;

    auto stage = [&](int buf, int k0) {
        #pragma unroll
        for (int tt = 0; tt < 2; tt++) {
            int r0 = wid * 32 + tt * 16;
            gload_lds16(A + (size_t)(p0 + r0 + srow16) * KC + k0 + scol8,
                        (char*)As[buf] + r0 * 64);
            gload_lds16(A + (size_t)(q0 + r0 + srow16) * KC + k0 + scol8,
                        (char*)Bs[buf] + r0 * 64);
        }
    };

    const int nst = KC >> 5;   // 36 steps
    stage(0, 0);
    __syncthreads();
    int cur = 0;
    for (int s = 0; s < nst; ++s) {
        if (s + 1 < nst) stage(cur ^ 1, (s + 1) << 5);
        const char* Ab = (const char*)As[cur];
        const char* Bb = (const char*)Bs[cur];
        bf16x8 af[4], bg[4];
        #pragma unroll
        for (int mi = 0; mi < 4; mi++) {
            int row = wr * 64 + mi * 16 + lane16;
            af[mi] = *(const bf16x8*)(Ab + row * 64 + kgrp * 16);
        }
        #pragma unroll
        for (int ni = 0; ni < 4; ni++) {
            int row = wc * 64 + ni * 16 + lane16;
            bg[ni] = *(const bf16x8*)(Bb + row * 64 + kgrp * 16);
        }
        #pragma unroll
        for (int mi = 0; mi < 4; mi++)
            #pragma unroll
            for (int ni = 0; ni < 4; ni++)
                acc[mi * 4 + ni] = __builtin_amdgcn_mfma_f32_16x16x32_bf16(
                    af[mi], bg[ni], acc[mi * 4 + ni], 0, 0, 0);
        __syncthreads();
        cur ^= 1;
    }

    float invq[4];
    #pragma unroll
    for (int ni = 0; ni < 4; ni++)
        invq[ni] = 1.0f / colnorm[q0 + wc * 64 + ni * 16 + lane16];
    float invp[4][4];
    #pragma unroll
    for (int mi = 0; mi < 4; mi++) {
        int rbase = p0 + wr * 64 + mi * 16 + kgrp * 4;
        #pragma unroll
        for (int j = 0; j < 4; j++)
            invp[mi][j] = 1.0f / colnorm[rbase + j];
    }
    #pragma unroll
    for (int mi = 0; mi < 4; mi++) {
        int rbase = p0 + wr * 64 + mi * 16 + kgrp * 4;
        #pragma unroll
        for (int ni = 0; ni < 4; ni++) {
            int col = q0 + wc * 64 + ni * 16 + lane16;
            f32x4 v = acc[mi * 4 + ni];
            #pragma unroll
            for (int j = 0; j < 4; j++)
                C[(size_t)(rbase + j) * NPIX + col] = v[j] * invq[ni];
            if (ti != tj) {
                float4 tv;
                tv.x = v[0] * invp[mi][0]; tv.y = v[1] * invp[mi][1];
                tv.z = v[2] * invp[mi][2]; tv.w = v[3] * invp[mi][3];
                *(float4*)&C[(size_t)col * NPIX + rbase] = tv;
            }
        }
    }
}

// ---------------- GEMM2: 128x128 tile, BK=32 dbuf (4 blocks/CU), batch-z --------
__global__ __launch_bounds__(256) void k_mfma_gemm(
    const __hip_bfloat16* __restrict__ A, const __hip_bfloat16* __restrict__ B,
    float* __restrict__ C, int Ka, int ldc, size_t sA, size_t sB, size_t sC) {
    __shared__ __align__(16) __hip_bfloat16 As[2][128 * 32];
    __shared__ __align__(16) __hip_bfloat16 Bs[2][128 * 32];
    const int zb = blockIdx.z;
    A += (size_t)zb * sA; B += (size_t)zb * sB; C += (size_t)zb * sC;
    const int tid = threadIdx.x;
    const int l = tid & 63;
    const int wid = tid >> 6;
    const int wr = wid >> 1, wc = wid & 1;
    const int lane16 = l & 15, kgrp = l >> 4;
    const int gx = gridDim.x;
    const int nwg = gx * gridDim.y;
    const int id0 = blockIdx.y * gx + blockIdx.x;
    const int swzid = (id0 & 7) * (nwg >> 3) + (id0 >> 3);
    const int p0 = (swzid / gx) * 128, q0 = (swzid % gx) * 128;
    const int srow16 = l >> 2;
    const int scol8 = (l & 3) * 8;

    f32x4 acc[16];
    f32x4 zf; zf[0] = 0.f; zf[1] = 0.f; zf[2] = 0.f; zf[3] = 0.f;
    #pragma unroll
    for (int i = 0; i < 16; i++) acc[i] = zf;

    auto stage = [&](int buf, int k0) {
        #pragma unroll
        for (int tt = 0; tt < 2; tt++) {
            int r0 = wid * 32 + tt * 16;
            gload_lds16(A + (size_t)(p0 + r0 + srow16) * Ka + k0 + scol8,
                        (char*)As[buf] + r0 * 64);
            gload_lds16(B + (size_t)(q0 + r0 + srow16) * Ka + k0 + scol8,
                        (char*)Bs[buf] + r0 * 64);
        }
    };

    const int nst = Ka >> 5;
    stage(0, 0);
    __syncthreads();
    int cur = 0;
    for (int s = 0; s < nst; ++s) {
        if (s + 1 < nst) stage(cur ^ 1, (s + 1) << 5);
        const char* Ab = (const char*)As[cur];
        const char* Bb = (const char*)Bs[cur];
        bf16x8 af[4], bg[4];
        #pragma unroll
        for (int mi = 0; mi < 4; mi++) {
            int row = wr * 64 + mi * 16 + lane16;
            af[mi] = *(const bf16x8*)(Ab + row * 64 + kgrp * 16);
        }
        #pragma unroll
        for (int ni = 0; ni < 4; ni++) {
            int row = wc * 64 + ni * 16 + lane16;
            bg[ni] = *(const bf16x8*)(Bb + row * 64 + kgrp * 16);
        }
        #pragma unroll
        for (int mi = 0; mi < 4; mi++)
            #pragma unroll
            for (int ni = 0; ni < 4; ni++)
                acc[mi * 4 + ni] = __builtin_amdgcn_mfma_f32_16x16x32_bf16(
                    af[mi], bg[ni], acc[mi * 4 + ni], 0, 0, 0);
        __syncthreads();
        cur ^= 1;
    }

    #pragma unroll
    for (int mi = 0; mi < 4; mi++) {
        int rbase = p0 + wr * 64 + mi * 16 + kgrp * 4;
        #pragma unroll
        for (int ni = 0; ni < 4; ni++) {
            int col = q0 + wc * 64 + ni * 16 + lane16;
            f32x4 v = acc[mi * 4 + ni];
            #pragma unroll
            for (int j = 0; j < 4; j++)
                C[(size_t)(rbase + j) * ldc + col] = v[j];
        }
    }
}

// ---------------- fuse + mask + softmax -> bf16 Y (XCD-contiguous rows) ----------
__global__ void k_fusesm(const float* __restrict__ S, const float* __restrict__ mmv,
                         __hip_bfloat16* __restrict__ Y) {
    int blk = blockIdx.x;
    int p = ((blk & 7) << 9) | (blk >> 3);
    int tid = threadIdx.x;
    __shared__ float z[NPIX];
    __shared__ float red[256];
    int cmp = ((p & 63) << 6) | (p >> 6);
    const float* rowp[3][3];
    #pragma unroll
    for (int ei = 0; ei < 3; ei++)
        #pragma unroll
        for (int di = 0; di < 3; di++) {
            int cp2 = cmp + ei - 1;
            const float* rp = nullptr;
            if (cp2 >= 0 && cp2 < NPIX) {
                int prm = ((cp2 & 63) << 6) | (cp2 >> 6);
                int pa = prm + di - 1;
                if (pa >= 0 && pa < NPIX) rp = S + (size_t)pa * NPIX;
            }
            rowp[ei][di] = rp;
        }
    float lmax = -1e30f;
    for (int q = tid; q < NPIX; q += 256) {
        int cmq = ((q & 63) << 6) | (q >> 6);
        float acc = 0.f;
        #pragma unroll
        for (int ei = 0; ei < 3; ei++) {
            int cq2 = cmq + ei - 1;
            if (cq2 < 0 || cq2 >= NPIX) continue;
            int qrm = ((cq2 & 63) << 6) | (cq2 >> 6);
            #pragma unroll
            for (int di = 0; di < 3; di++) {
                int qa = qrm + di - 1;
                const float* rp = rowp[ei][di];
                if (rp && qa >= 0 && qa < NPIX) acc += rp[qa];
            }
        }
        float zz = acc * mmv[q] * SCALEF;
        z[q] = zz;
        lmax = fmaxf(lmax, zz);
    }
    red[tid] = lmax; __syncthreads();
    for (int st = 128; st > 0; st >>= 1) {
        if (tid < st) red[tid] = fmaxf(red[tid], red[tid + st]);
        __syncthreads();
    }
    float gmax = red[0];
    __syncthreads();
    float lsum = 0.f;
    for (int q = tid; q < NPIX; q += 256) {
        float e = expf(z[q] - gmax);
        z[q] = e;
        lsum += e;
    }
    red[tid] = lsum; __syncthreads();
    for (int st = 128; st > 0; st >>= 1) {
        if (tid < st) red[tid] += red[tid + st];
        __syncthreads();
    }
    float invs = 1.0f / red[0];
    for (int q = tid; q < NPIX; q += 256)
        Y[(size_t)p * NPIX + q] = __float2bfloat16(z[q] * invs * mmv[q]);
}

// ---------------- deconv gather + concat with x -> hi/lo bf16 ----------------
__global__ void k_deconv(const float* __restrict__ O2, const float* __restrict__ x,
                         __hip_bfloat16* __restrict__ ych, __hip_bfloat16* __restrict__ ycl,
                         int bsel, size_t sO2) {
    int idx = blockIdx.x * blockDim.x + threadIdx.x;
    int b = (bsel >= 0) ? bsel : (idx >> 19);
    int loc = idx & ((1 << 19) - 1);
    int p = loc >> 7, c = loc & 127;
    int h = p >> 6, w = p & 63;
    const float* O2b = O2 + ((bsel >= 0) ? 0 : (size_t)b * sO2);
    float acc = 0.f;
    #pragma unroll
    for (int u = 0; u < 3; u++) {
        int hh = h + 1 - u;
        if (hh < 0 || hh >= HW) continue;
        #pragma unroll
        for (int v = 0; v < 3; v++) {
            int ww = w + 1 - v;
            if (ww < 0 || ww >= HW) continue;
            acc += O2b[(size_t)(hh * HW + ww) * KC + (u * 3 + v) * CCH + c];
        }
    }
    float xv = x[((size_t)b * NPIX + p) * CCH + c];
    size_t base = (size_t)b * NPIX * 256 + (size_t)p * 256;
    __hip_bfloat16 ah = __float2bfloat16(acc);
    __hip_bfloat16 xh = __float2bfloat16(xv);
    ych[base + c] = ah;
    ych[base + 128 + c] = xh;
    ycl[base + c] = __float2bfloat16(acc - __bfloat162float(ah));
    ycl[base + 128 + c] = __float2bfloat16(xv - __bfloat162float(xh));
}

// ---------------- split+transpose weights Wc/W2 ----------------
__global__ void k_wsplit(const float* __restrict__ Wc, const float* __restrict__ W2,
                         __hip_bfloat16* __restrict__ wtc_h, __hip_bfloat16* __restrict__ wtc_l,
                         __hip_bfloat16* __restrict__ wt2_h, __hip_bfloat16* __restrict__ wt2_l) {
    int idx = blockIdx.x * blockDim.x + threadIdx.x;
    int m = idx / (128 * KF);
    int rem = idx - m * 128 * KF;
    int j = rem / KF, k = rem - j * KF;
    const float* src = m ? W2 : Wc;
    float v = src[(size_t)k * 128 + j];
    __hip_bfloat16 hi = __float2bfloat16(v);
    __hip_bfloat16 lo = __float2bfloat16(v - __bfloat162float(hi));
    (m ? wt2_h : wtc_h)[(size_t)j * KF + k] = hi;
    (m ? wt2_l : wtc_l)[(size_t)j * KF + k] = lo;
}

// ---------------- split+transpose W1 ----------------
__global__ void k_wsplit1(const float* __restrict__ W1,
                          __hip_bfloat16* __restrict__ w1t_h, __hip_bfloat16* __restrict__ w1t_l) {
    int idx = blockIdx.x * blockDim.x + threadIdx.x;
    int j = idx >> 8, k = idx & 255;
    float v = W1[(size_t)k * 128 + j];
    __hip_bfloat16 hi = __float2bfloat16(v);
    __hip_bfloat16 lo = __float2bfloat16(v - __bfloat162float(hi));
    w1t_h[(size_t)j * 256 + k] = hi;
    w1t_l[(size_t)j * 256 + k] = lo;
}

__global__ void k_zero(float* __restrict__ zp) {
    if (threadIdx.x < 64) zp[threadIdx.x] = 0.f;
}

// ---------------- final conv via split-bf16 MFMA, W1 gate folded in ----------------
__global__ __launch_bounds__(256) void k_final_mfma(
    const __hip_bfloat16* __restrict__ ych, const __hip_bfloat16* __restrict__ ycl,
    const __hip_bfloat16* __restrict__ wtc_h, const __hip_bfloat16* __restrict__ wtc_l,
    const __hip_bfloat16* __restrict__ wt2_h, const __hip_bfloat16* __restrict__ wt2_l,
    const __hip_bfloat16* __restrict__ w1t_h, const __hip_bfloat16* __restrict__ w1t_l,
    const float* __restrict__ bc, const float* __restrict__ b1,
    const float* __restrict__ b2, const float* __restrict__ zpage,
    float* __restrict__ outp) {
    __shared__ __align__(16) char As_h[2048], As_l[2048];
    __shared__ __align__(16) char Bs_h[32768], Bs_l[32768];
    const int tid = threadIdx.x;
    const int lane = tid & 63, wv = tid >> 6;
    const int lane16 = lane & 15, kgrp = lane >> 4;
    const int gblk = blockIdx.x;
    const int b = gblk >> 8;
    const int p0l = (gblk & 255) * 16;
    const __hip_bfloat16* ybh = ych + (size_t)b * NPIX * 256;
    const __hip_bfloat16* ybl = ycl + (size_t)b * NPIX * 256;
    const int srow8 = lane >> 3;
    const int c16 = lane & 7;
    const int swc = c16 ^ srow8;

    const int arow = ((wv & 1) << 3) + srow8;
    const int apr = p0l + arow;
    const int ah_ = apr >> 6, aw_ = apr & 63;
    char* const a_ldst = ((wv >> 1) ? As_l : As_h) + ((wv & 1) << 10);
    const __hip_bfloat16* const a_base = (wv >> 1) ? ybl : ybh;

    const char* bsrc_h[8];
    const char* bsrc_l[8];
    #pragma unroll
    for (int r = 0; r < 8; r++) {
        int q = r * 4 + wv;
        int row = q * 8 + srow8;
        const __hip_bfloat16* mh = (row < 128) ? (wtc_h + (size_t)row * KF)
                                               : (wt2_h + (size_t)(row - 128) * KF);
        const __hip_bfloat16* ml = (row < 128) ? (wtc_l + (size_t)row * KF)
                                               : (wt2_l + (size_t)(row - 128) * KF);
        bsrc_h[r] = (const char*)(mh + swc * 8);
        bsrc_l[r] = (const char*)(ml + swc * 8);
    }

    f32x4 acc[4];
    f32x4 zf; zf[0] = 0.f; zf[1] = 0.f; zf[2] = 0.f; zf[3] = 0.f;
    #pragma unroll
    for (int f = 0; f < 4; f++) acc[f] = zf;

    for (int it = 0; it < 36; ++it) {
        const int k0 = it * 64;
        const int tap = k0 >> 8, i0 = k0 & 255;
        const int di = tap / 3, dj = tap - di * 3;
        {
            int hh = ah_ + di - 1, ww = aw_ + dj - 1;
            const void* src;
            if (hh >= 0 && hh < HW && ww >= 0 && ww < HW)
                src = a_base + ((size_t)(hh * HW + ww) * 256 + i0 + swc * 8);
            else
                src = (const char*)zpage + c16 * 16;
            gload_lds16(src, a_ldst);
        }
        #pragma unroll
        for (int r = 0; r < 8; r++) {
            int q = r * 4 + wv;
            gload_lds16(bsrc_h[r] + (size_t)it * 128, Bs_h + (q << 10));
            gload_lds16(bsrc_l[r] + (size_t)it * 128, Bs_l + (q << 10));
        }
        __syncthreads();
        #pragma unroll
        for (int kh = 0; kh < 2; kh++) {
            const int chunk = kgrp + 4 * kh;
            const int abyte = lane16 * 128 + ((chunk ^ (lane16 & 7)) << 4);
            bf16x8 ah = *(const bf16x8*)(As_h + abyte);
            bf16x8 al = *(const bf16x8*)(As_l + abyte);
            #pragma unroll
            for (int f = 0; f < 4; f++) {
                int brow = ((f < 2) ? 0 : 128) + wv * 32 + ((f & 1) << 4) + lane16;
                int bbyte = brow * 128 + ((chunk ^ (brow & 7)) << 4);
                bf16x8 bh = *(const bf16x8*)(Bs_h + bbyte);
                bf16x8 bl = *(const bf16x8*)(Bs_l + bbyte);
                acc[f] = __builtin_amdgcn_mfma_f32_16x16x32_bf16(ah, bh, acc[f], 0, 0, 0);
                acc[f] = __builtin_amdgcn_mfma_f32_16x16x32_bf16(ah, bl, acc[f], 0, 0, 0);
                acc[f] = __builtin_amdgcn_mfma_f32_16x16x32_bf16(al, bh, acc[f], 0, 0, 0);
            }
        }
        __syncthreads();
    }

    f32x4 acc1[2];
    acc1[0] = zf; acc1[1] = zf;
    for (int ki = 0; ki < 4; ++ki) {
        gload_lds16(a_base + ((size_t)(ah_ * HW + aw_) * 256 + ki * 64 + swc * 8), a_ldst);
        #pragma unroll
        for (int r = 0; r < 4; r++) {
            int q = r * 4 + wv;
            int row = q * 8 + srow8;
            gload_lds16((const char*)(w1t_h + (size_t)row * 256 + ki * 64 + swc * 8),
                        Bs_h + (q << 10));
            gload_lds16((const char*)(w1t_l + (size_t)row * 256 + ki * 64 + swc * 8),
                        Bs_l + (q << 10));
        }
        __syncthreads();
        #pragma unroll
        for (int kh = 0; kh < 2; kh++) {
            const int chunk = kgrp + 4 * kh;
            const int abyte = lane16 * 128 + ((chunk ^ (lane16 & 7)) << 4);
            bf16x8 ah = *(const bf16x8*)(As_h + abyte);
            bf16x8 al = *(const bf16x8*)(As_l + abyte);
            #pragma unroll
            for (int g = 0; g < 2; g++) {
                int brow = wv * 32 + (g << 4) + lane16;
                int bbyte = brow * 128 + ((chunk ^ (brow & 7)) << 4);
                bf16x8 bh = *(const bf16x8*)(Bs_h + bbyte);
                bf16x8 bl = *(const bf16x8*)(Bs_l + bbyte);
                acc1[g] = __builtin_amdgcn_mfma_f32_16x16x32_bf16(ah, bh, acc1[g], 0, 0, 0);
                acc1[g] = __builtin_amdgcn_mfma_f32_16x16x32_bf16(ah, bl, acc1[g], 0, 0, 0);
                acc1[g] = __builtin_amdgcn_mfma_f32_16x16x32_bf16(al, bh, acc1[g], 0, 0, 0);
            }
        }
        __syncthreads();
    }

    #pragma unroll
    for (int fc = 0; fc < 2; fc++) {
        int col = wv * 32 + (fc << 4) + lane16;
        float bcv = bc[col], b1v = b1[col], b2v = b2[col];
        #pragma unroll
        for (int j = 0; j < 4; j++) {
            int px = kgrp * 4 + j;
            size_t gp = (size_t)gblk * 16 + px;
            float core = acc[fc][j] + bcv;
            float g2 = acc[fc + 2][j] + b2v;
            float a1 = acc1[fc][j] + b1v;
            float s1 = 1.f / (1.f + expf(-a1));
            float s2 = 1.f / (1.f + expf(-g2));
            outp[gp * 128 + col] = 0.5f * (s1 + s2) * core;
        }
    }
}

extern "C" void kernel_launch(void* const* d_in, const int* in_sizes, int n_in,
                              void* d_out, int out_size, void* d_ws, size_t ws_size,
                              hipStream_t stream) {
    const float* x    = (const float*)d_in[0];
    const float* mask = (const float*)d_in[1];
    const float* Wc   = (const float*)d_in[2];
    const float* bc   = (const float*)d_in[3];
    const float* W1   = (const float*)d_in[4];
    const float* b1   = (const float*)d_in[5];
    const float* W2   = (const float*)d_in[6];
    const float* b2   = (const float*)d_in[7];
    float* outp = (float*)d_out;

    char* ws = (char*)d_ws;
    const size_t NEED_BIG = 211190016UL;
    const bool big = (ws_size >= NEED_BIG);

    __hip_bfloat16* Pbf;  __hip_bfloat16* Pt0;  size_t ptStride;
    float* S;  __hip_bfloat16* Y0;  size_t yStride;
    float* O2; size_t o2Stride;
    __hip_bfloat16 *ych, *ycl, *wtc_h, *wtc_l, *wt2_h, *wt2_l, *w1t_h, *w1t_l;
    float *colnorm, *mmv, *zpage;

    if (big) {
        Pbf   = (__hip_bfloat16*)(ws + 0);
        Pt0   = (__hip_bfloat16*)(ws + 9437184UL);   ptStride = (size_t)KC * NPIX;
        S     = (float*)(ws + 28311552UL);
        Y0    = (__hip_bfloat16*)(ws + 95420416UL);  yStride  = (size_t)NPIX * NPIX;
        O2    = (float*)(ws + 162529280UL);          o2Stride = (size_t)NPIX * KC;
        ych   = (__hip_bfloat16*)(ws + 200278016UL);
        ycl   = (__hip_bfloat16*)(ws + 204472320UL);
        wtc_h = (__hip_bfloat16*)(ws + 208666624UL);
        wtc_l = (__hip_bfloat16*)(ws + 209256448UL);
        wt2_h = (__hip_bfloat16*)(ws + 209846272UL);
        wt2_l = (__hip_bfloat16*)(ws + 210436096UL);
        w1t_h = (__hip_bfloat16*)(ws + 211025920UL);
        w1t_l = (__hip_bfloat16*)(ws + 211091456UL);
        colnorm = (float*)(ws + 211156992UL);
        mmv     = (float*)(ws + 211173376UL);
        zpage   = (float*)(ws + 211189760UL);
    } else {
        Pbf   = (__hip_bfloat16*)(ws + 0);
        Pt0   = (__hip_bfloat16*)(ws + 9437184UL);   ptStride = 0;
        S     = (float*)(ws + 18874368UL);
        Y0    = (__hip_bfloat16*)(ws + 85983232UL);  yStride  = 0;
        O2    = (float*)(ws + 119537664UL);          o2Stride = 0;
        ych   = (__hip_bfloat16*)(ws + 138412032UL);
        ycl   = (__hip_bfloat16*)(ws + 142606336UL);
        wtc_h = (__hip_bfloat16*)(ws + 146800640UL);
        wtc_l = (__hip_bfloat16*)(ws + 147390464UL);
        wt2_h = (__hip_bfloat16*)(ws + 147980288UL);
        wt2_l = (__hip_bfloat16*)(ws + 148570112UL);
        w1t_h = (__hip_bfloat16*)(ws + 149159936UL);
        w1t_l = (__hip_bfloat16*)(ws + 149225472UL);
        colnorm = (float*)(ws + 149291008UL);
        mmv     = (float*)(ws + 149307392UL);
        zpage   = (float*)(ws + 149323776UL);
    }

    hipLaunchKernelGGL(k_zero, dim3(1), dim3(64), 0, stream, zpage);
    hipLaunchKernelGGL(k_wsplit, dim3(2 * 128 * KF / 256), dim3(256), 0, stream,
                       Wc, W2, wtc_h, wtc_l, wt2_h, wt2_l);
    hipLaunchKernelGGL(k_wsplit1, dim3(128 * 256 / 256), dim3(256), 0, stream,
                       W1, w1t_h, w1t_l);

    for (int b = 0; b < 2; b++) {
        hipLaunchKernelGGL(k_build_Pbf, dim3((NPIX * KC) / 256), dim3(256), 0, stream, x, Pbf, b);
        hipLaunchKernelGGL(k_build_Pt, dim3((KC * NPIX) / 256), dim3(256), 0, stream,
                           x, Pt0 + (size_t)b * ptStride, b);
        hipLaunchKernelGGL(k_colnorm, dim3(NPIX), dim3(256), 0, stream, Pbf, colnorm);
        hipLaunchKernelGGL(k_mm, dim3(NPIX / 256), dim3(256), 0, stream, mask, mmv, b);
        hipLaunchKernelGGL(k_gemm_sym, dim3(528), dim3(256), 0, stream, Pbf, S, colnorm);
        hipLaunchKernelGGL(k_fusesm, dim3(NPIX), dim3(256), 0, stream,
                           S, mmv, Y0 + (size_t)b * yStride);
        if (!big) {
            hipLaunchKernelGGL(k_mfma_gemm, dim3(9, 32, 1), dim3(256), 0, stream,
                               Y0, Pt0, O2, NPIX, KC, (size_t)0, (size_t)0, (size_t)0);
            hipLaunchKernelGGL(k_deconv, dim3((NPIX * CCH) / 256), dim3(256), 0, stream,
                               O2, x, ych, ycl, b, (size_t)0);
        }
    }
    if (big) {
        hipLaunchKernelGGL(k_mfma_gemm, dim3(9, 32, 2), dim3(256), 0, stream,
                           Y0, Pt0, O2, NPIX, KC, yStride, ptStride, o2Stride);
        hipLaunchKernelGGL(k_deconv, dim3((2 * NPIX * CCH) / 256), dim3(256), 0, stream,
                           O2, x, ych, ycl, -1, o2Stride);
    }
    hipLaunchKernelGGL(k_final_mfma, dim3(512), dim3(256), 0, stream,
                       ych, ycl, wtc_h, wtc_l, wt2_h, wt2_l, w1t_h, w1t_l,
                       bc, b1, b2, zpage, outp);
}